// Round 1
// baseline (12916.481 us; speedup 1.0000x reference)
//
#include <hip/hip_runtime.h>
#include <hip/hip_bf16.h>
#include <stdint.h>

#define T_STEPS 256
#define BATCH   64
#define HID     512
#define HALF    256
#define NCOLS   1536              // [zr1:512 | g1:256 | zr2:512 | g2:256]
#define MROWS   (T_STEPS * BATCH) // 16384
#define SLICE_N 100
#define SAVED_OFF (2 * BATCH * HID) // 65536 floats into d_out

typedef short bf16x8 __attribute__((ext_vector_type(8)));
typedef float f32x4  __attribute__((ext_vector_type(4)));

__device__ __forceinline__ f32x4 mfma16(bf16x8 a, bf16x8 b, f32x4 c) {
  return __builtin_amdgcn_mfma_f32_16x16x32_bf16(a, b, c, 0, 0, 0);
}
__device__ __forceinline__ float sigm_f(float x) {
  return 1.f / (1.f + __expf(-x));
}
__device__ __forceinline__ float tanh_f(float x) {
  x = fminf(fmaxf(x, -30.f), 30.f);
  float e = __expf(-2.f * x);
  return (1.f - e) / (1.f + e);
}

// ---------------------------------------------------------------- prep weights
struct LayerPtrs {
  const float *Wz1, *bz1, *Wg1, *bg1, *Wz2, *bz2, *Wg2, *bg2;
};

// UT:  [1536][256]  bf16  (recurrent weights, transposed: UT[col][k])
// WxT: [1536][512]  bf16  (x-part weights,   transposed: WxT[col][k])
// biasAll: [1536]   f32
__global__ void prep_weights(LayerPtrs p, __hip_bfloat16* __restrict__ UT,
                             __hip_bfloat16* __restrict__ WxT,
                             float* __restrict__ biasAll) {
  int i = blockIdx.x * blockDim.x + threadIdx.x;
  const int total = NCOLS * 768;
  if (i < total) {
    int c = i / 768, kk = i % 768;
    const float* W; int nc, cc;
    if (c < 512)       { W = p.Wz1; nc = 512; cc = c;        }
    else if (c < 768)  { W = p.Wg1; nc = 256; cc = c - 512;  }
    else if (c < 1280) { W = p.Wz2; nc = 512; cc = c - 768;  }
    else               { W = p.Wg2; nc = 256; cc = c - 1280; }
    if (kk < 256)
      UT[(size_t)c * 256 + kk] = __float2bfloat16(W[(size_t)(512 + kk) * nc + cc]);
    else
      WxT[(size_t)c * 512 + (kk - 256)] = __float2bfloat16(W[(size_t)(kk - 256) * nc + cc]);
  } else if (i < total + NCOLS) {
    int c = i - total;
    const float* b; int cc;
    if (c < 512)       { b = p.bz1; cc = c;        }
    else if (c < 768)  { b = p.bg1; cc = c - 512;  }
    else if (c < 1280) { b = p.bz2; cc = c - 768;  }
    else               { b = p.bg2; cc = c - 1280; }
    biasAll[c] = b[cc];
  }
}

// ---------------------------------------------------------------- embed gather
__global__ void embed_gather(const int* __restrict__ seq, const float* __restrict__ emb,
                             __hip_bfloat16* __restrict__ X0) {
  int i = blockIdx.x * blockDim.x + threadIdx.x; // over 16384*128
  int row = i >> 7, c4 = (i & 127) * 4;
  int idx = seq[row];
  float4 v = *(const float4*)&emb[(size_t)idx * HID + c4];
  union { __hip_bfloat16 h[4]; uint2 u; } pk;
  pk.h[0] = __float2bfloat16(v.x);
  pk.h[1] = __float2bfloat16(v.y);
  pk.h[2] = __float2bfloat16(v.z);
  pk.h[3] = __float2bfloat16(v.w);
  *(uint2*)&X0[(size_t)row * HID + c4] = pk.u;
}

// ---------------------------------------------------------------- P = A @ WxT^T + bias
// A: [M=16384][512] bf16 row-major. WxT: [1536][512] bf16 (col-major weights).
// P: [16384][1536] f32.  Grid: (24 Nblocks, 256 Mblocks), 256 threads (4 waves).
__global__ __launch_bounds__(256) void gemm_p(const __hip_bfloat16* __restrict__ A,
                                              const __hip_bfloat16* __restrict__ WT,
                                              const float* __restrict__ bias,
                                              float* __restrict__ P) {
  const int tid = threadIdx.x;
  const int lane = tid & 63, w = tid >> 6;
  const int lrow = lane & 15, lgrp = lane >> 4;
  const int n0 = blockIdx.x * 64, m0 = blockIdx.y * 64;
  const int wm = w & 1, wn = w >> 1;
  __shared__ __hip_bfloat16 As[64][72];
  f32x4 acc[2][2];
#pragma unroll
  for (int a = 0; a < 2; ++a)
#pragma unroll
    for (int b = 0; b < 2; ++b) acc[a][b] = (f32x4){0.f, 0.f, 0.f, 0.f};

  const int lr = tid >> 2, lc = (tid & 3) * 16;
  for (int k0 = 0; k0 < 512; k0 += 64) {
    *(uint4*)&As[lr][lc]     = *(const uint4*)&A[((size_t)m0 + lr) * 512 + k0 + lc];
    *(uint4*)&As[lr][lc + 8] = *(const uint4*)&A[((size_t)m0 + lr) * 512 + k0 + lc + 8];
    __syncthreads();
#pragma unroll
    for (int kt = 0; kt < 2; ++kt) {
      bf16x8 a0 = *(const bf16x8*)&As[wm * 32 + lrow][kt * 32 + lgrp * 8];
      bf16x8 a1 = *(const bf16x8*)&As[wm * 32 + 16 + lrow][kt * 32 + lgrp * 8];
      bf16x8 b0 = *(const bf16x8*)&WT[((size_t)n0 + wn * 32 + lrow) * 512 + k0 + kt * 32 + lgrp * 8];
      bf16x8 b1 = *(const bf16x8*)&WT[((size_t)n0 + wn * 32 + 16 + lrow) * 512 + k0 + kt * 32 + lgrp * 8];
      acc[0][0] = mfma16(a0, b0, acc[0][0]);
      acc[0][1] = mfma16(a0, b1, acc[0][1]);
      acc[1][0] = mfma16(a1, b0, acc[1][0]);
      acc[1][1] = mfma16(a1, b1, acc[1][1]);
    }
    __syncthreads();
  }
#pragma unroll
  for (int mt = 0; mt < 2; ++mt)
#pragma unroll
    for (int nt = 0; nt < 2; ++nt)
#pragma unroll
      for (int rr = 0; rr < 4; ++rr) {
        int row = m0 + wm * 32 + mt * 16 + lgrp * 4 + rr;
        int col = n0 + wn * 32 + nt * 16 + lrow;
        P[(size_t)row * NCOLS + col] = acc[mt][nt][rr] + bias[col];
      }
}

// ---------------------------------------------------------------- recurrence
// One WG = 16 batch rows, 16 waves (1024 thr). Weights register-resident.
// UTl: this layer's [1536][256] bf16. P: [16384][1536] f32 (this layer's x-parts+bias).
// Hseq (LAYER==0): [t][64][512] bf16 output sequence for layer-1 GEMM.
template <int LAYER>
__global__ __launch_bounds__(1024) void rec_kernel(const __hip_bfloat16* __restrict__ UTl,
                                                   const float* __restrict__ P,
                                                   float* __restrict__ out,
                                                   __hip_bfloat16* __restrict__ Hseq) {
  const int tid = threadIdx.x;
  const int lane = tid & 63, w = tid >> 6;
  const int lrow = lane & 15, lgrp = lane >> 4;
  const int b0 = blockIdx.x * 16;

  __shared__ float zf[16][257];
  __shared__ __hip_bfloat16 h1b[16][264], h2b[16][264], agb[16][264];

  // init
  for (int i = tid; i < 16 * 264; i += 1024) {
    int r = i / 264, c = i % 264;
    __hip_bfloat16 z0 = __float2bfloat16(0.f);
    h1b[r][c] = z0; h2b[r][c] = z0; agb[r][c] = z0;
  }
  if (LAYER == 1) {
    for (int i = tid; i < 16 * SLICE_N; i += 1024)
      out[SAVED_OFF + (size_t)(b0 + i / SLICE_N) * SLICE_N + (i % SLICE_N)] = 0.f;
  }

  // register-resident weight fragments
  bf16x8 fz1[2][8], fz2[2][8], fg1[8], fg2[8];
#pragma unroll
  for (int nt = 0; nt < 2; ++nt)
#pragma unroll
    for (int kt = 0; kt < 8; ++kt) {
      fz1[nt][kt] = *(const bf16x8*)&UTl[(size_t)(0 + w * 32 + nt * 16 + lrow) * 256 + kt * 32 + lgrp * 8];
      fz2[nt][kt] = *(const bf16x8*)&UTl[(size_t)(768 + w * 32 + nt * 16 + lrow) * 256 + kt * 32 + lgrp * 8];
    }
#pragma unroll
  for (int kt = 0; kt < 8; ++kt) {
    fg1[kt] = *(const bf16x8*)&UTl[(size_t)(512 + w * 16 + lrow) * 256 + kt * 32 + lgrp * 8];
    fg2[kt] = *(const bf16x8*)&UTl[(size_t)(1280 + w * 16 + lrow) * 256 + kt * 32 + lgrp * 8];
  }

  // master h state in registers: this wave owns h1[*, w*16+lrow] and h2[*, w*16+lrow]
  float hreg1[4] = {0.f, 0.f, 0.f, 0.f};
  float hreg2[4] = {0.f, 0.f, 0.f, 0.f};

  float pc[24], pn[24];
  auto loadP = [&](float* d, int t) {
    const float* base = P + ((size_t)t * BATCH + b0 + lgrp * 4) * NCOLS;
#pragma unroll
    for (int rr = 0; rr < 4; ++rr) {
      const float* bp = base + (size_t)rr * NCOLS;
      d[rr]      = bp[w * 32 + lrow];            // zr1 nt=0
      d[4 + rr]  = bp[w * 32 + 16 + lrow];       // zr1 nt=1
      d[8 + rr]  = bp[512 + w * 16 + lrow];      // g1
      d[12 + rr] = bp[768 + w * 32 + lrow];      // zr2 nt=0
      d[16 + rr] = bp[768 + w * 32 + 16 + lrow]; // zr2 nt=1
      d[20 + rr] = bp[1280 + w * 16 + lrow];     // g2
    }
  };
  loadP(pc, 0);
  __syncthreads();

  const float Q23 = 8388608.f, IQ23 = 1.f / 8388608.f;
  const float Q10 = 1024.f,    IQ10 = 1.f / 1024.f;

  for (int t = 0; t < T_STEPS; ++t) {
    // ---- stage 1: zr1 = sigma(P + h2 @ Uzr1)
    {
      f32x4 acc0 = (f32x4){0.f, 0.f, 0.f, 0.f}, acc1 = (f32x4){0.f, 0.f, 0.f, 0.f};
#pragma unroll
      for (int kt = 0; kt < 8; ++kt) {
        bf16x8 a = *(const bf16x8*)&h2b[lrow][kt * 32 + lgrp * 8];
        acc0 = mfma16(a, fz1[0][kt], acc0);
        acc1 = mfma16(a, fz1[1][kt], acc1);
      }
      if (t + 1 < T_STEPS) loadP(pn, t + 1); // prefetch next step's P
      if (w < 8) {
#pragma unroll
        for (int nt = 0; nt < 2; ++nt)
#pragma unroll
          for (int rr = 0; rr < 4; ++rr) {
            int row = lgrp * 4 + rr, col = w * 32 + nt * 16 + lrow;
            float pre = (nt ? acc1[rr] : acc0[rr]) + pc[nt * 4 + rr];
            zf[row][col] = 0.875f * sigm_f(pre) + 0.125f;
          }
      } else {
#pragma unroll
        for (int nt = 0; nt < 2; ++nt)
#pragma unroll
          for (int rr = 0; rr < 4; ++rr) {
            int row = lgrp * 4 + rr, col = (w - 8) * 32 + nt * 16 + lrow;
            float pre = (nt ? acc1[rr] : acc0[rr]) + pc[nt * 4 + rr];
            float r1 = sigm_f(pre);
            float h2v = __bfloat162float(h2b[row][col]);
            agb[row][col] = __float2bfloat16(r1 * h2v);
          }
      }
    }
    __syncthreads();

    // ---- stage 2: g1 = tanh(P + (r1*h2) @ Ug1); h1 update
    {
      f32x4 acc = (f32x4){0.f, 0.f, 0.f, 0.f};
#pragma unroll
      for (int kt = 0; kt < 8; ++kt) {
        bf16x8 a = *(const bf16x8*)&agb[lrow][kt * 32 + lgrp * 8];
        acc = mfma16(a, fg1[kt], acc);
      }
      int col = w * 16 + lrow;
#pragma unroll
      for (int rr = 0; rr < 4; ++rr) {
        int row = lgrp * 4 + rr;
        float g = tanh_f(acc[rr] + pc[8 + rr]);
        float z = zf[row][col];
        float zq = floorf(z * Q10) * IQ10;
        float h = hreg1[rr];
        h = floorf(h * zq * Q23) * IQ23;
        h = h + rintf((1.f - z) * g * Q23) * IQ23;
        hreg1[rr] = h;
        h1b[row][col] = __float2bfloat16(h);
        if (LAYER == 0)
          Hseq[((size_t)t * BATCH + b0 + row) * HID + col] = __float2bfloat16(h);
        if (LAYER == 1 && col < SLICE_N)
          out[SAVED_OFF + (size_t)(t + 1) * (BATCH * SLICE_N) + (b0 + row) * SLICE_N + col] = h;
        if (t == T_STEPS - 1)
          out[(size_t)LAYER * (BATCH * HID) + (b0 + row) * HID + col] = h;
      }
    }
    __syncthreads();

    // ---- stage 3: zr2 = sigma(P + h1 @ Uzr2)
    {
      f32x4 acc0 = (f32x4){0.f, 0.f, 0.f, 0.f}, acc1 = (f32x4){0.f, 0.f, 0.f, 0.f};
#pragma unroll
      for (int kt = 0; kt < 8; ++kt) {
        bf16x8 a = *(const bf16x8*)&h1b[lrow][kt * 32 + lgrp * 8];
        acc0 = mfma16(a, fz2[0][kt], acc0);
        acc1 = mfma16(a, fz2[1][kt], acc1);
      }
      if (w < 8) {
#pragma unroll
        for (int nt = 0; nt < 2; ++nt)
#pragma unroll
          for (int rr = 0; rr < 4; ++rr) {
            int row = lgrp * 4 + rr, col = w * 32 + nt * 16 + lrow;
            float pre = (nt ? acc1[rr] : acc0[rr]) + pc[12 + nt * 4 + rr];
            zf[row][col] = 0.875f * sigm_f(pre) + 0.125f;
          }
      } else {
#pragma unroll
        for (int nt = 0; nt < 2; ++nt)
#pragma unroll
          for (int rr = 0; rr < 4; ++rr) {
            int row = lgrp * 4 + rr, col = (w - 8) * 32 + nt * 16 + lrow;
            float pre = (nt ? acc1[rr] : acc0[rr]) + pc[12 + nt * 4 + rr];
            float r2 = sigm_f(pre);
            float h1v = __bfloat162float(h1b[row][col]);
            agb[row][col] = __float2bfloat16(r2 * h1v);
          }
      }
    }
    __syncthreads();

    // ---- stage 4: g2 = tanh(P + (r2*h1) @ Ug2); h2 update
    {
      f32x4 acc = (f32x4){0.f, 0.f, 0.f, 0.f};
#pragma unroll
      for (int kt = 0; kt < 8; ++kt) {
        bf16x8 a = *(const bf16x8*)&agb[lrow][kt * 32 + lgrp * 8];
        acc = mfma16(a, fg2[kt], acc);
      }
      int col = w * 16 + lrow;
#pragma unroll
      for (int rr = 0; rr < 4; ++rr) {
        int row = lgrp * 4 + rr;
        float g = tanh_f(acc[rr] + pc[20 + rr]);
        float z = zf[row][col];
        float zq = floorf(z * Q10) * IQ10;
        float h = hreg2[rr];
        h = floorf(h * zq * Q23) * IQ23;
        h = h + rintf((1.f - z) * g * Q23) * IQ23;
        hreg2[rr] = h;
        h2b[row][col] = __float2bfloat16(h);
        if (LAYER == 0)
          Hseq[((size_t)t * BATCH + b0 + row) * HID + HALF + col] = __float2bfloat16(h);
        if (t == T_STEPS - 1)
          out[(size_t)LAYER * (BATCH * HID) + (b0 + row) * HID + HALF + col] = h;
      }
    }
    if (t + 1 < T_STEPS) {
#pragma unroll
      for (int i = 0; i < 24; ++i) pc[i] = pn[i];
    }
    __syncthreads();
  }
}

// ---------------------------------------------------------------- launch
extern "C" void kernel_launch(void* const* d_in, const int* in_sizes, int n_in,
                              void* d_out, int out_size, void* d_ws, size_t ws_size,
                              hipStream_t stream) {
  const int*   seq = (const int*)d_in[0];
  const float* emb = (const float*)d_in[1];
  auto F = [&](int i) { return (const float*)d_in[i]; };
  LayerPtrs L0 = {F(2), F(3), F(4), F(5), F(6), F(7), F(8), F(9)};
  LayerPtrs L1 = {F(10), F(11), F(12), F(13), F(14), F(15), F(16), F(17)};

  uint8_t* wp = (uint8_t*)d_ws;
  float* P = (float*)wp;                     wp += (size_t)MROWS * NCOLS * 4;   // 100.7 MB
  __hip_bfloat16* X0 = (__hip_bfloat16*)wp;  wp += (size_t)MROWS * HID * 2;     // 16.8 MB
  __hip_bfloat16* H0 = (__hip_bfloat16*)wp;  wp += (size_t)MROWS * HID * 2;     // 16.8 MB
  __hip_bfloat16* UT = (__hip_bfloat16*)wp;  wp += (size_t)2 * NCOLS * 256 * 2; // 1.6 MB
  __hip_bfloat16* WxT = (__hip_bfloat16*)wp; wp += (size_t)2 * NCOLS * 512 * 2; // 3.1 MB
  float* biasAll = (float*)wp;               wp += (size_t)2 * NCOLS * 4;

  float* out = (float*)d_out;

  const int prepN = (NCOLS * 768 + NCOLS + 255) / 256;
  prep_weights<<<prepN, 256, 0, stream>>>(L0, UT, WxT, biasAll);
  prep_weights<<<prepN, 256, 0, stream>>>(L1, UT + (size_t)NCOLS * 256,
                                          WxT + (size_t)NCOLS * 512, biasAll + NCOLS);
  embed_gather<<<(MROWS * 128) / 256, 256, 0, stream>>>(seq, emb, X0);

  gemm_p<<<dim3(24, 256), 256, 0, stream>>>(X0, WxT, biasAll, P);
  rec_kernel<0><<<4, 1024, 0, stream>>>(UT, P, out, H0);
  gemm_p<<<dim3(24, 256), 256, 0, stream>>>(H0, WxT + (size_t)NCOLS * 512, biasAll + NCOLS, P);
  rec_kernel<1><<<4, 1024, 0, stream>>>(UT + (size_t)NCOLS * 256, P, out, nullptr);
}